// Round 11
// baseline (127.898 us; speedup 1.0000x reference)
//
#include <hip/hip_runtime.h>
#include <hip/hip_bf16.h>
#include <math.h>

#define BTOT 32768

typedef _Float16 f16x8 __attribute__((ext_vector_type(8)));
typedef _Float16 f16x4 __attribute__((ext_vector_type(4)));
typedef float    f32x4 __attribute__((ext_vector_type(4)));

__device__ __forceinline__ float ldin(const void* p, int i, int f32f) {
  return f32f ? ((const float*)p)[i]
              : __bfloat162float(((const __hip_bfloat16*)p)[i]);
}

__device__ __forceinline__ f32x4 MFMA(f16x8 a, f16x8 b, f32x4 c) {
  return __builtin_amdgcn_mfma_f32_16x16x32_f16(a, b, c, 0, 0, 0);
}

__device__ __forceinline__ float tanh_fast(float x) {
  float e = __expf(2.f * x);
  return 1.f - 2.f * __builtin_amdgcn_rcpf(e + 1.f);
}

__device__ __forceinline__ float redq(float v) {
  v += __shfl_xor(v, 16, 64);
  v += __shfl_xor(v, 32, 64);
  return v;
}

// fragment-linear index: (h,k) -> slot; A/B-frag reads lane-contiguous 16B.
__device__ __forceinline__ int widx(int h, int k) {
  return ((h >> 4) << 10) + ((k >> 5) << 9) + (((k >> 3) & 3) << 7) + ((h & 15) << 3) + (k & 7);
}

// ws fp16 layout: VW2 0 | VW2T 4096 | HW2 8192 | HW2T 12288 | HW3 16384 |
//                 HW3T 20480 | W1Vh 24576 | W1Vl 25088 | W1Hh 25600 | W1Hl 26112
#define OFF_VW2   0
#define OFF_VW2T  4096
#define OFF_HW2   8192
#define OFF_HW2T  12288
#define OFF_HW3   16384
#define OFF_HW3T  20480
#define OFF_W1VH  24576
#define OFF_W1VL  25088
#define OFF_W1HH  25600
#define OFF_W1HL  26112

// ===========================================================================
// Prep: write fragment-linear fp16 weight panels (+transposes) and hi/lo W1
// into ws. Runs every launch (ws is re-poisoned by the harness each call).
// ===========================================================================
__global__ __launch_bounds__(256) void prep_kernel(
    const void* px, const void* pVW1, const void* pVW2,
    const void* pHW1, const void* pHW2, const void* pHW3, _Float16* wsp)
{
  __shared__ int sCnt;
  const int tid = threadIdx.x;
  if (tid == 0) sCnt = 0;
  __syncthreads();
  {
    const unsigned short* xb = (const unsigned short*)px;
    int good = 0;
#pragma unroll
    for (int i = 0; i < 2; ++i) {
      int ex = (xb[tid * 2 + i] >> 7) & 0xFF;
      good += (ex >= 97 && ex <= 157) ? 1 : 0;
    }
    atomicAdd(&sCnt, good);
  }
  __syncthreads();
  const int f32f = (sCnt >= 435) ? 0 : 1;

  const int t = blockIdx.x * 256 + tid;   // 0..4095
  int h = t >> 6, k = t & 63;
  int fw = widx(h, k), tw = widx(k, h);
  _Float16 v;
  v = (_Float16)ldin(pVW2, t, f32f); wsp[OFF_VW2 + fw] = v; wsp[OFF_VW2T + tw] = v;
  v = (_Float16)ldin(pHW2, t, f32f); wsp[OFF_HW2 + fw] = v; wsp[OFF_HW2T + tw] = v;
  v = (_Float16)ldin(pHW3, t, f32f); wsp[OFF_HW3 + fw] = v; wsp[OFF_HW3T + tw] = v;
  if (t < 512) {
    float f = ldin(pVW1, t, f32f); _Float16 hh = (_Float16)f;
    wsp[OFF_W1VH + t] = hh; wsp[OFF_W1VL + t] = (_Float16)(f - (float)hh);
    f = ldin(pHW1, t, f32f); hh = (_Float16)f;
    wsp[OFF_W1HH + t] = hh; wsp[OFF_W1HL + t] = (_Float16)(f - (float)hh);
  }
}

// ===========================================================================
// Main: 2048 blocks x 128 thr. Block = one 16-elem tile; the 2 waves split
// the 64 h-rows (wave w owns h-tiles {2w,2w+1}). Weight A-frags stream from
// ws (L1/L2-hot, coalesced 16B/lane). Act (fp16 hi) in LDS, block barriers.
// V/H chains interleaved. QP tail: Schur ADMM on 16 threads.
// out (f32): u[2B] | relax[B] | V[B] | Vdot[B] | H[B] | Hdot[B]
// ===========================================================================
__global__ __launch_bounds__(128, 4) void main_kernel(
    const void* px, const void* pVb1, const void* pVb2,
    const void* pHb1, const void* pHb2, const void* pHb3,
    const void* pHW4, const void* pHb4, const void* pG0, const void* pK,
    const void* pVW1, const void* pHW1,
    const _Float16* wsp, float* out)
{
  __shared__ __align__(16) _Float16 actV[1024], actH[1024];
  __shared__ __align__(16) float sQPp[2][16][8];
  __shared__ __align__(16) float sVb1[64], sVb2[64], sHb1[64], sHb2[64], sHb3[64], sW4[64];
  __shared__ __align__(16) float sWGV0[64], sWGV1[64], sWGH0[64], sWGH1[64];
  __shared__ float sKv[16], sHb4v;
  __shared__ int sCnt;

  const int tid = threadIdx.x, lane = tid & 63, wave = tid >> 6;
  const int m = lane & 15, q = lane >> 4;
  const int ro = lane * 8;                 // frag offset (== q*128 + m*8)
  const int e0 = blockIdx.x * 16;

  // ---- dtype detection: 128 thr x 4 halves = 512 samples ----
  if (tid == 0) sCnt = 0;
  __syncthreads();
  {
    const unsigned short* xb = (const unsigned short*)px;
    int good = 0;
#pragma unroll
    for (int i = 0; i < 4; ++i) {
      int ex = (xb[tid * 4 + i] >> 7) & 0xFF;
      good += (ex >= 97 && ex <= 157) ? 1 : 0;
    }
    atomicAdd(&sCnt, good);
  }
  __syncthreads();
  const int f32f = (sCnt >= 435) ? 0 : 1;
  const bool wsplit = (f32f != 0);

  // ---- per-block constants ----
  if (tid < 64) {
    float a0 = 0.f, a1 = 0.f, b0 = 0.f, b1 = 0.f;
#pragma unroll
    for (int nn = 0; nn < 8; ++nn) {
      float g0 = ldin(pG0, 2 * nn, f32f), g1 = ldin(pG0, 2 * nn + 1, f32f);
      float wv = ldin(pVW1, tid * 8 + nn, f32f), wh = ldin(pHW1, tid * 8 + nn, f32f);
      a0 += wv * g0; a1 += wv * g1; b0 += wh * g0; b1 += wh * g1;
    }
    sWGV0[tid] = a0; sWGV1[tid] = a1; sWGH0[tid] = b0; sWGH1[tid] = b1;
    sVb1[tid] = ldin(pVb1, tid, f32f);
    sVb2[tid] = ldin(pVb2, tid, f32f);
    sHb1[tid] = ldin(pHb1, tid, f32f);
    sHb2[tid] = ldin(pHb2, tid, f32f);
    sHb3[tid] = ldin(pHb3, tid, f32f);
    sW4[tid]  = ldin(pHW4, tid, f32f);
  }
  if (tid < 16) sKv[tid] = ldin(pK, tid, f32f);
  if (tid == 0) sHb4v = ldin(pHb4, 0, f32f);

  f16x8 zf;
#pragma unroll
  for (int i = 0; i < 8; ++i) zf[i] = (_Float16)0.f;

  // x B-frag (hi/lo) in registers (lanes<16)
  f16x8 xbh = zf, xbl = zf;
  if (lane < 16) {
#pragma unroll
    for (int n = 0; n < 8; ++n) {
      float v = ldin(px, (e0 + m) * 8 + n, f32f);
      _Float16 hh = (_Float16)v;
      xbh[n] = hh; xbl[n] = (_Float16)(v - (float)hh);
    }
  }
  __syncthreads();

  // half-GEMM (this wave's 2 h-tiles) from a ws panel + act B-frags
  auto hgemm = [&](int poff, const _Float16* a_, f32x4* acc) {
    f16x8 b0 = *(const f16x8*)(a_ + ro);
    f16x8 b1 = *(const f16x8*)(a_ + 512 + ro);
#pragma unroll
    for (int i = 0; i < 2; ++i) {
      const _Float16* ap = wsp + poff + (2 * wave + i) * 1024 + ro;
      f32x4 c = {0.f, 0.f, 0.f, 0.f};
      c = MFMA(*(const f16x8*)ap, b0, c);
      c = MFMA(*(const f16x8*)(ap + 512), b1, c);
      acc[i] = c;
    }
  };
  // store this wave's 2 h-tiles of C-layout vals into an act buffer
  auto wstore = [&](const f32x4* vals, _Float16* a_) {
#pragma unroll
    for (int i = 0; i < 2; ++i) {
      int ht = 2 * wave + i;
      int aw = ((ht >> 1) << 9) + (((ht & 1) * 2 + (q >> 1)) << 7) + m * 8 + ((q & 1) << 2);
      f16x4 vh;
#pragma unroll
      for (int r = 0; r < 4; ++r) vh[r] = (_Float16)vals[i][r];
      *(f16x4*)(a_ + aw) = vh;
    }
  };
  auto l1gemm = [&](int hoff, int loff, f32x4* acc) {
#pragma unroll
    for (int i = 0; i < 2; ++i) {
      int ht = 2 * wave + i;
      f16x8 afh = zf, afl = zf;
      if (lane < 16) {
        afh = *(const f16x8*)(wsp + hoff + (ht * 16 + m) * 8);
        afl = *(const f16x8*)(wsp + loff + (ht * 16 + m) * 8);
      }
      f32x4 c = {0.f, 0.f, 0.f, 0.f};
      c = MFMA(afh, xbh, c);
      c = MFMA(afh, xbl, c);
      if (wsplit) c = MFMA(afl, xbh, c);
      acc[i] = c;
    }
  };

  f32x4 accV[2], accH[2], z1V[2], z1H[2], d1V[2], d1H[2], d2H[2], tvV[2], tvH[2];

  // ===== stage A: layer-1 both nets =====
  l1gemm(OFF_W1VH, OFF_W1VL, accV);
  l1gemm(OFF_W1HH, OFF_W1HL, accH);
#pragma unroll
  for (int i = 0; i < 2; ++i) {
    int hb = (2 * wave + i) * 16 + q * 4;
    z1V[i] = accV[i]; z1H[i] = accH[i];
    f32x4 bV = *(const f32x4*)&sVb1[hb];
    f32x4 bH = *(const f32x4*)&sHb1[hb];
#pragma unroll
    for (int r = 0; r < 4; ++r) {
      float t = tanh_fast(z1V[i][r] + bV[r]);
      tvV[i][r] = t; d1V[i][r] = 1.f - t * t;
      t = tanh_fast(z1H[i][r] + bH[r]);
      tvH[i][r] = t; d1H[i][r] = 1.f - t * t;
    }
  }
  wstore(tvV, actV); wstore(tvH, actH);
  __syncthreads();

  // ===== stage B: layer-2 both nets =====
  hgemm(OFF_VW2, actV, accV);
  hgemm(OFF_HW2, actH, accH);
  float pV = 0.f;
#pragma unroll
  for (int i = 0; i < 2; ++i) {
    int hb = (2 * wave + i) * 16 + q * 4;
    f32x4 bV = *(const f32x4*)&sVb2[hb];
    f32x4 bH = *(const f32x4*)&sHb2[hb];
#pragma unroll
    for (int r = 0; r < 4; ++r) {
      float t = tanh_fast(accV[i][r] + bV[r]);
      pV += t * t;
      tvV[i][r] = t * (1.f - t * t);        // a = t2*d2
      t = tanh_fast(accH[i][r] + bH[r]);
      tvH[i][r] = t; d2H[i][r] = 1.f - t * t;
    }
  }
  __syncthreads();                           // all B-frag reads done
  wstore(tvV, actV); wstore(tvH, actH);
  __syncthreads();

  // ===== stage C: V backward (W2^T) + H layer-3 (W3) =====
  hgemm(OFF_VW2T, actV, accV);               // wk
  hgemm(OFF_HW3, actH, accH);
  float pgvx = 0.f, plv0 = 0.f, plv1 = 0.f, pH = 0.f;
#pragma unroll
  for (int i = 0; i < 2; ++i) {
    int hb = (2 * wave + i) * 16 + q * 4;
    f32x4 g0 = *(const f32x4*)&sWGV0[hb];
    f32x4 g1 = *(const f32x4*)&sWGV1[hb];
    f32x4 bH = *(const f32x4*)&sHb3[hb];
    f32x4 w4 = *(const f32x4*)&sW4[hb];
#pragma unroll
    for (int r = 0; r < 4; ++r) {
      float wt = accV[i][r] * d1V[i][r];
      pgvx += wt * z1V[i][r];
      plv0 += wt * g0[r]; plv1 += wt * g1[r];
      float t = tanh_fast(accH[i][r] + bH[r]);
      pH += t * w4[r];
      tvH[i][r] = w4[r] * (1.f - t * t);     // v4
    }
  }
  __syncthreads();
  wstore(tvH, actH);
  __syncthreads();

  // ===== stage D: H backward (W3^T) =====
  hgemm(OFF_HW3T, actH, accH);               // v3
#pragma unroll
  for (int i = 0; i < 2; ++i)
#pragma unroll
    for (int r = 0; r < 4; ++r) tvH[i][r] = accH[i][r] * d2H[i][r];   // bb
  __syncthreads();
  wstore(tvH, actH);
  __syncthreads();

  // ===== stage E: H backward (W2^T) =====
  hgemm(OFF_HW2T, actH, accH);               // v2
  float pghx = 0.f, plh0 = 0.f, plh1 = 0.f;
#pragma unroll
  for (int i = 0; i < 2; ++i) {
    int hb = (2 * wave + i) * 16 + q * 4;
    f32x4 g0 = *(const f32x4*)&sWGH0[hb];
    f32x4 g1 = *(const f32x4*)&sWGH1[hb];
#pragma unroll
    for (int r = 0; r < 4; ++r) {
      float wt = accH[i][r] * d1H[i][r];
      pghx += wt * z1H[i][r];
      plh0 += wt * g0[r]; plh1 += wt * g1[r];
    }
  }

  // ---- per-wave partials (each wave covers its 32 h-rows) ----
  {
    float a0 = redq(plh0), a1 = redq(plh1), a2 = redq(plv0), a3 = redq(plv1);
    float a4 = redq(pghx), a5 = redq(pgvx), a6 = redq(pV), a7 = redq(pH);
    if (lane < 16) {
      sQPp[wave][lane][0] = a0; sQPp[wave][lane][1] = a1;
      sQPp[wave][lane][2] = a2; sQPp[wave][lane][3] = a3;
      sQPp[wave][lane][4] = a4; sQPp[wave][lane][5] = a5;
      sQPp[wave][lane][6] = a6; sQPp[wave][lane][7] = a7;
    }
  }
  __syncthreads();

  // ====== QP tail: 16 threads, Schur-complement ADMM (verified R9/R10) =====
  if (tid >= 16) return;
  const int e = e0 + tid;
  float gh0 = sQPp[0][tid][0] + sQPp[1][tid][0];
  float gh1 = sQPp[0][tid][1] + sQPp[1][tid][1];
  float gv0 = sQPp[0][tid][2] + sQPp[1][tid][2];
  float gv1 = sQPp[0][tid][3] + sQPp[1][tid][3];
  float ghx = sQPp[0][tid][4] + sQPp[1][tid][4];
  float gvx = sQPp[0][tid][5] + sQPp[1][tid][5];
  float V   = 0.5f * (sQPp[0][tid][6] + sQPp[1][tid][6]);
  float H   = sQPp[0][tid][7] + sQPp[1][tid][7] + sHb4v;
  out[98304 + e]  = V;
  out[163840 + e] = H;

  const float im = 1.0f / 1.2f;
  const float sg = 1e-6f;

  float un0 = 0.f, un1 = 0.f;
#pragma unroll
  for (int n = 0; n < 8; ++n) {
    float xv = ldin(px, e * 8 + n, f32f);
    un0 -= xv * sKv[2 * n];
    un1 -= xv * sKv[2 * n + 1];
  }

  float lo0 = ghx - H;
  float hi1 = gvx - V;
  float lo2 = ghx * im - H;
  float hi3 = gvx * im - V;
  float qv0 = -2.f * un0, qv1 = -2.f * un1;

  const float d  = 2.f + sg;
  const float rd = 1.f / d;
  const float al = 1.f + im * im;
  const float be = al * (1.f - rd);
  float S00 = be * (gh0 * gh0 + gv0 * gv0) + d;
  float S11 = be * (gh1 * gh1 + gv1 * gv1) + d;
  float S01 = be * (gh0 * gh1 + gv0 * gv1);
  float idet = 1.f / (S00 * S11 - S01 * S01);
  float i00 = S11 * idet, i11 = S00 * idet, i01 = -S01 * idet;

  float X0 = 0.f, X1 = 0.f, X2 = 0.f, X3 = 0.f, X4 = 0.f, X5 = 0.f;
  float Z[8] = {0.f, 0.f, 0.f, 0.f, 0.f, 0.f, 0.f, 0.f};
  float Y[8] = {0.f, 0.f, 0.f, 0.f, 0.f, 0.f, 0.f, 0.f};

#pragma unroll 1
  for (int it = 0; it < 80; ++it) {
    float t0 = Z[0] - Y[0], t1 = Z[1] - Y[1], t2 = Z[2] - Y[2], t3 = Z[3] - Y[3];
    float t4 = Z[4] - Y[4], t5 = Z[5] - Y[5], t6 = Z[6] - Y[6], t7 = Z[7] - Y[7];
    float tauh = t0 + im * t2, tauv = t1 + im * t3;
    float b0 = sg * X0 - qv0 + gh0 * tauh + gv0 * tauv;
    float b1 = sg * X1 - qv1 + gh1 * tauh + gv1 * tauv;
    float b2 = sg * X2 - 100.f - t1 + t4;
    float b3 = sg * X3 - 100.f - t3 + t5;
    float b4 = sg * X4 - 50.f + t0 + t6;
    float b5 = sg * X5 - 50.f + t2 + t7;
    float p  = b2 + im * b3;
    float s2 = b4 + im * b5;
    float cb0 = gh0 * s2 - gv0 * p;
    float cb1 = gh1 * s2 - gv1 * p;
    float u0b = b0 - cb0 * rd;
    float u1b = b1 - cb1 * rd;
    X0 = i00 * u0b + i01 * u1b;
    X1 = i01 * u0b + i11 * u1b;
    float gdH = gh0 * X0 + gh1 * X1;
    float gdV = gv0 * X0 + gv1 * X1;
    X2 = (b2 + gdV) * rd;
    X3 = (b3 + im * gdV) * rd;
    X4 = (b4 - gdH) * rd;
    X5 = (b5 - im * gdH) * rd;
    float zt0 = gdH + X4;
    float zt1 = gdV - X2;
    float zt2 = gdH * im + X5;
    float zt3 = gdV * im - X3;

    float v, zn;
    v = zt0 + Y[0]; zn = fmaxf(v, lo0); Y[0] += zt0 - zn; Z[0] = zn;
    v = zt1 + Y[1]; zn = fminf(v, hi1); Y[1] += zt1 - zn; Z[1] = zn;
    v = zt2 + Y[2]; zn = fmaxf(v, lo2); Y[2] += zt2 - zn; Z[2] = zn;
    v = zt3 + Y[3]; zn = fminf(v, hi3); Y[3] += zt3 - zn; Z[3] = zn;
    v = X2 + Y[4];  zn = fmaxf(v, 0.f); Y[4] += X2 - zn;  Z[4] = zn;
    v = X3 + Y[5];  zn = fmaxf(v, 0.f); Y[5] += X3 - zn;  Z[5] = zn;
    v = X4 + Y[6];  zn = fmaxf(v, 0.f); Y[6] += X4 - zn;  Z[6] = zn;
    v = X5 + Y[7];  zn = fmaxf(v, 0.f); Y[7] += X5 - zn;  Z[7] = zn;
  }

  float relax = 0.5f * (X2 + X3);
  const float cc = 0.5f * (1.f + im);
  float Vdot = cc * (gv0 * X0 + gv1 * X1 - gvx);
  float Hdot = cc * (gh0 * X0 + gh1 * X1 - ghx);

  out[2 * e]      = X0;
  out[2 * e + 1]  = X1;
  out[65536 + e]  = relax;
  out[131072 + e] = Vdot;
  out[196608 + e] = Hdot;
}

extern "C" void kernel_launch(void* const* d_in, const int* in_sizes, int n_in,
                              void* d_out, int out_size, void* d_ws, size_t ws_size,
                              hipStream_t stream) {
  float* out = (float*)d_out;
  _Float16* wsp = (_Float16*)d_ws;
  prep_kernel<<<16, 256, 0, stream>>>(
      d_in[0], d_in[1], d_in[3], d_in[5], d_in[7], d_in[9], wsp);
  main_kernel<<<2048, 128, 0, stream>>>(
      d_in[0], d_in[2], d_in[4], d_in[6], d_in[8], d_in[10],
      d_in[11], d_in[12], d_in[13], d_in[14],
      d_in[1], d_in[5],
      wsp, out);
}

// Round 12
// 109.533 us; speedup vs baseline: 1.1677x; 1.1677x over previous
//
#include <hip/hip_runtime.h>
#include <hip/hip_bf16.h>
#include <math.h>

#define BTOT 32768

typedef _Float16 f16x8 __attribute__((ext_vector_type(8)));
typedef _Float16 f16x4 __attribute__((ext_vector_type(4)));
typedef float    f32x4 __attribute__((ext_vector_type(4)));

__device__ __forceinline__ float ldin(const void* p, int i, int f32f) {
  return f32f ? ((const float*)p)[i]
              : __bfloat162float(((const __hip_bfloat16*)p)[i]);
}

__device__ __forceinline__ f32x4 MFMA(f16x8 a, f16x8 b, f32x4 c) {
  return __builtin_amdgcn_mfma_f32_16x16x32_f16(a, b, c, 0, 0, 0);
}

__device__ __forceinline__ float tanh_fast(float x) {
  float e = __expf(2.f * x);
  return 1.f - 2.f * __builtin_amdgcn_rcpf(e + 1.f);
}

__device__ __forceinline__ float redq(float v) {
  v += __shfl_xor(v, 16, 64);
  v += __shfl_xor(v, 32, 64);
  return v;
}

// fragment-linear index: (h,k) -> slot; A/B-frag reads lane-contiguous 16B.
__device__ __forceinline__ int widx(int h, int k) {
  return ((h >> 4) << 10) + ((k >> 5) << 9) + (((k >> 3) & 3) << 7) + ((h & 15) << 3) + (k & 7);
}

// ---- ws layout ----
// fp16 panels:
#define OFF_VW2   0
#define OFF_VW2T  4096
#define OFF_HW2   8192
#define OFF_HW2T  12288
#define OFF_HW3   16384
#define OFF_HW3T  20480
#define OFF_W1VH  24576
#define OFF_W1VL  25088
#define OFF_W1HH  25600
#define OFF_W1HL  26112
// f32 constants region (at f16-offset 28672 = byte 57344):
#define CF_BASE   28672
#define C_WGV0 0
#define C_WGV1 64
#define C_WGH0 128
#define C_WGH1 192
#define C_VB1  256
#define C_VB2  320
#define C_HB1  384
#define C_HB2  448
#define C_HB3  512
#define C_W4   576
#define C_K    640
#define C_HB4  656
#define C_FLAG 657
#define C_N    658

// ===========================================================================
// Prep: detection + fragment-linear fp16 panels (+transposes) + hi/lo W1 +
// all f32 constants (WG dot products, biases, K, Hb4, dtype flag) into ws.
// ===========================================================================
__global__ __launch_bounds__(256) void prep_kernel(
    const void* px, const void* pVW1, const void* pVW2,
    const void* pHW1, const void* pHW2, const void* pHW3,
    const void* pVb1, const void* pVb2, const void* pHb1, const void* pHb2,
    const void* pHb3, const void* pHW4, const void* pHb4,
    const void* pG0, const void* pK, _Float16* wsp)
{
  __shared__ int sCnt;
  const int tid = threadIdx.x;
  if (tid == 0) sCnt = 0;
  __syncthreads();
  {
    const unsigned short* xb = (const unsigned short*)px;
    int good = 0;
#pragma unroll
    for (int i = 0; i < 2; ++i) {
      int ex = (xb[tid * 2 + i] >> 7) & 0xFF;
      good += (ex >= 97 && ex <= 157) ? 1 : 0;
    }
    atomicAdd(&sCnt, good);
  }
  __syncthreads();
  const int f32f = (sCnt >= 435) ? 0 : 1;   // >=85% of 512 sane -> bf16 inputs

  const int t = blockIdx.x * 256 + tid;     // 0..4095
  int h = t >> 6, k = t & 63;
  int fw = widx(h, k), tw = widx(k, h);
  _Float16 v;
  v = (_Float16)ldin(pVW2, t, f32f); wsp[OFF_VW2 + fw] = v; wsp[OFF_VW2T + tw] = v;
  v = (_Float16)ldin(pHW2, t, f32f); wsp[OFF_HW2 + fw] = v; wsp[OFF_HW2T + tw] = v;
  v = (_Float16)ldin(pHW3, t, f32f); wsp[OFF_HW3 + fw] = v; wsp[OFF_HW3T + tw] = v;
  if (t < 512) {
    float f = ldin(pVW1, t, f32f); _Float16 hh = (_Float16)f;
    wsp[OFF_W1VH + t] = hh; wsp[OFF_W1VL + t] = (_Float16)(f - (float)hh);
    f = ldin(pHW1, t, f32f); hh = (_Float16)f;
    wsp[OFF_W1HH + t] = hh; wsp[OFF_W1HL + t] = (_Float16)(f - (float)hh);
  }
  if (blockIdx.x == 0) {
    float* wsF = (float*)(wsp + CF_BASE);
    if (tid < 64) {
      float a0 = 0.f, a1 = 0.f, b0 = 0.f, b1 = 0.f;
#pragma unroll
      for (int nn = 0; nn < 8; ++nn) {
        float g0 = ldin(pG0, 2 * nn, f32f), g1 = ldin(pG0, 2 * nn + 1, f32f);
        float wv = ldin(pVW1, tid * 8 + nn, f32f), wh = ldin(pHW1, tid * 8 + nn, f32f);
        a0 += wv * g0; a1 += wv * g1; b0 += wh * g0; b1 += wh * g1;
      }
      wsF[C_WGV0 + tid] = a0; wsF[C_WGV1 + tid] = a1;
      wsF[C_WGH0 + tid] = b0; wsF[C_WGH1 + tid] = b1;
      wsF[C_VB1 + tid] = ldin(pVb1, tid, f32f);
      wsF[C_VB2 + tid] = ldin(pVb2, tid, f32f);
      wsF[C_HB1 + tid] = ldin(pHb1, tid, f32f);
      wsF[C_HB2 + tid] = ldin(pHb2, tid, f32f);
      wsF[C_HB3 + tid] = ldin(pHb3, tid, f32f);
      wsF[C_W4  + tid] = ldin(pHW4, tid, f32f);
    }
    if (tid < 16) wsF[C_K + tid] = ldin(pK, tid, f32f);
    if (tid == 0) { wsF[C_HB4] = ldin(pHb4, 0, f32f); ((int*)wsF)[C_FLAG] = f32f; }
  }
}

// ===========================================================================
// Main: 512 blocks x 512 thr = 64 elems/block. 4 wave-pairs; pair p owns the
// 16-elem tile p, its 2 waves split the 64 h-rows (sub owns h-tiles
// {2sub,2sub+1}). Ping-pong fp16 act buffers (2 per net per pair) -> 6
// barriers. Weight A-frags stream from ws (L1/L2-hot). QP tail: full 64-lane
// Schur ADMM on wave 0. out (f32): u|relax|V|Vdot|H|Hdot.
// ===========================================================================
__global__ __launch_bounds__(512, 4) void main_kernel(
    const void* px, const _Float16* wsp, float* out)
{
  __shared__ __align__(16) _Float16 sAct[4][4][1024];   // [pair][V0,V1,H0,H1]
  __shared__ __align__(16) float sQPp[8][16][12];
  __shared__ __align__(16) float sC[C_N];

  const int tid = threadIdx.x, lane = tid & 63, wave = tid >> 6;
  const int pair = wave >> 1, sub = wave & 1;
  const int m = lane & 15, q = lane >> 4;
  const int ro = lane * 8;
  const int e0 = blockIdx.x * 64 + pair * 16;

  const float* wsF = (const float*)(wsp + CF_BASE);
  for (int i = tid; i < C_N; i += 512) sC[i] = wsF[i];
  const int f32f = ((const int*)wsF)[C_FLAG];
  const bool wsplit = (f32f != 0);

  f16x8 zf;
#pragma unroll
  for (int i = 0; i < 8; ++i) zf[i] = (_Float16)0.f;

  // x B-frag (hi/lo) in registers (lanes<16 of each wave; same within pair)
  f16x8 xbh = zf, xbl = zf;
  if (lane < 16) {
#pragma unroll
    for (int n = 0; n < 8; ++n) {
      float v = ldin(px, (e0 + m) * 8 + n, f32f);
      _Float16 hh = (_Float16)v;
      xbh[n] = hh; xbl[n] = (_Float16)(v - (float)hh);
    }
  }
  __syncthreads();   // sync#0: sC ready

  // u_nom = -(x @ K): sub==0 wave, lanes<16, from x regs + sC
  if (sub == 0 && lane < 16) {
    float un0 = 0.f, un1 = 0.f;
#pragma unroll
    for (int n = 0; n < 8; ++n) {
      float xv = (float)xbh[n] + (float)xbl[n];
      un0 -= xv * sC[C_K + 2 * n];
      un1 -= xv * sC[C_K + 2 * n + 1];
    }
    sQPp[wave][m][8] = un0; sQPp[wave][m][9] = un1;
  }

  _Float16* bufV0 = sAct[pair][0];
  _Float16* bufV1 = sAct[pair][1];
  _Float16* bufH0 = sAct[pair][2];
  _Float16* bufH1 = sAct[pair][3];

  auto hgemm = [&](int poff, const _Float16* a_, f32x4* acc) {
    f16x8 b0 = *(const f16x8*)(a_ + ro);
    f16x8 b1 = *(const f16x8*)(a_ + 512 + ro);
#pragma unroll
    for (int i = 0; i < 2; ++i) {
      const _Float16* ap = wsp + poff + (2 * sub + i) * 1024 + ro;
      f32x4 c = {0.f, 0.f, 0.f, 0.f};
      c = MFMA(*(const f16x8*)ap, b0, c);
      c = MFMA(*(const f16x8*)(ap + 512), b1, c);
      acc[i] = c;
    }
  };
  auto wstore = [&](const f32x4* vals, _Float16* a_) {
#pragma unroll
    for (int i = 0; i < 2; ++i) {
      int ht = 2 * sub + i;
      int aw = ((ht >> 1) << 9) + (((ht & 1) * 2 + (q >> 1)) << 7) + m * 8 + ((q & 1) << 2);
      f16x4 vh;
#pragma unroll
      for (int r = 0; r < 4; ++r) vh[r] = (_Float16)vals[i][r];
      *(f16x4*)(a_ + aw) = vh;
    }
  };
  auto l1gemm = [&](int hoff, int loff, f32x4* acc) {
#pragma unroll
    for (int i = 0; i < 2; ++i) {
      int ht = 2 * sub + i;
      f16x8 afh = zf, afl = zf;
      if (lane < 16) {
        afh = *(const f16x8*)(wsp + hoff + (ht * 16 + m) * 8);
        afl = *(const f16x8*)(wsp + loff + (ht * 16 + m) * 8);
      }
      f32x4 c = {0.f, 0.f, 0.f, 0.f};
      c = MFMA(afh, xbh, c);
      c = MFMA(afh, xbl, c);
      if (wsplit) c = MFMA(afl, xbh, c);
      acc[i] = c;
    }
  };

  f32x4 accV[2], accH[2], z1V[2], z1H[2], d1V[2], d1H[2], d2H[2], tvV[2], tvH[2];

  // ===== stage A: layer-1 both nets -> buf0 =====
  l1gemm(OFF_W1VH, OFF_W1VL, accV);
  l1gemm(OFF_W1HH, OFF_W1HL, accH);
#pragma unroll
  for (int i = 0; i < 2; ++i) {
    int hb = (2 * sub + i) * 16 + q * 4;
    z1V[i] = accV[i]; z1H[i] = accH[i];
    f32x4 bV = *(const f32x4*)&sC[C_VB1 + hb];
    f32x4 bH = *(const f32x4*)&sC[C_HB1 + hb];
#pragma unroll
    for (int r = 0; r < 4; ++r) {
      float t = tanh_fast(z1V[i][r] + bV[r]);
      tvV[i][r] = t; d1V[i][r] = 1.f - t * t;
      t = tanh_fast(z1H[i][r] + bH[r]);
      tvH[i][r] = t; d1H[i][r] = 1.f - t * t;
    }
  }
  wstore(tvV, bufV0); wstore(tvH, bufH0);
  __syncthreads();   // sync#1

  // ===== stage B: layer-2 both nets: read buf0 -> write buf1 =====
  hgemm(OFF_VW2, bufV0, accV);
  hgemm(OFF_HW2, bufH0, accH);
  float pV = 0.f;
#pragma unroll
  for (int i = 0; i < 2; ++i) {
    int hb = (2 * sub + i) * 16 + q * 4;
    f32x4 bV = *(const f32x4*)&sC[C_VB2 + hb];
    f32x4 bH = *(const f32x4*)&sC[C_HB2 + hb];
#pragma unroll
    for (int r = 0; r < 4; ++r) {
      float t = tanh_fast(accV[i][r] + bV[r]);
      pV += t * t;
      tvV[i][r] = t * (1.f - t * t);          // a = t2*d2
      t = tanh_fast(accH[i][r] + bH[r]);
      tvH[i][r] = t; d2H[i][r] = 1.f - t * t;
    }
  }
  wstore(tvV, bufV1); wstore(tvH, bufH1);
  __syncthreads();   // sync#2

  // ===== stage C: V bwd (W2^T on bufV1) + H layer-3 (W3 on bufH1 -> bufH0) =====
  hgemm(OFF_VW2T, bufV1, accV);               // wk
  hgemm(OFF_HW3, bufH1, accH);
  float pgvx = 0.f, plv0 = 0.f, plv1 = 0.f, pH = 0.f;
#pragma unroll
  for (int i = 0; i < 2; ++i) {
    int hb = (2 * sub + i) * 16 + q * 4;
    f32x4 g0 = *(const f32x4*)&sC[C_WGV0 + hb];
    f32x4 g1 = *(const f32x4*)&sC[C_WGV1 + hb];
    f32x4 bH = *(const f32x4*)&sC[C_HB3 + hb];
    f32x4 w4 = *(const f32x4*)&sC[C_W4 + hb];
#pragma unroll
    for (int r = 0; r < 4; ++r) {
      float wt = accV[i][r] * d1V[i][r];
      pgvx += wt * z1V[i][r];
      plv0 += wt * g0[r]; plv1 += wt * g1[r];
      float t = tanh_fast(accH[i][r] + bH[r]);
      pH += t * w4[r];
      tvH[i][r] = w4[r] * (1.f - t * t);      // v4
    }
  }
  wstore(tvH, bufH0);
  __syncthreads();   // sync#3

  // ===== stage D: H bwd (W3^T on bufH0) -> bufH1 =====
  hgemm(OFF_HW3T, bufH0, accH);               // v3
#pragma unroll
  for (int i = 0; i < 2; ++i)
#pragma unroll
    for (int r = 0; r < 4; ++r) tvH[i][r] = accH[i][r] * d2H[i][r];   // bb
  wstore(tvH, bufH1);
  __syncthreads();   // sync#4

  // ===== stage E: H bwd (W2^T on bufH1) =====
  hgemm(OFF_HW2T, bufH1, accH);               // v2
  float pghx = 0.f, plh0 = 0.f, plh1 = 0.f;
#pragma unroll
  for (int i = 0; i < 2; ++i) {
    int hb = (2 * sub + i) * 16 + q * 4;
    f32x4 g0 = *(const f32x4*)&sC[C_WGH0 + hb];
    f32x4 g1 = *(const f32x4*)&sC[C_WGH1 + hb];
#pragma unroll
    for (int r = 0; r < 4; ++r) {
      float wt = accH[i][r] * d1H[i][r];
      pghx += wt * z1H[i][r];
      plh0 += wt * g0[r]; plh1 += wt * g1[r];
    }
  }

  // ---- per-wave partials (this wave's 32 h-rows) ----
  {
    float a0 = redq(plh0), a1 = redq(plh1), a2 = redq(plv0), a3 = redq(plv1);
    float a4 = redq(pghx), a5 = redq(pgvx), a6 = redq(pV), a7 = redq(pH);
    if (lane < 16) {
      sQPp[wave][lane][0] = a0; sQPp[wave][lane][1] = a1;
      sQPp[wave][lane][2] = a2; sQPp[wave][lane][3] = a3;
      sQPp[wave][lane][4] = a4; sQPp[wave][lane][5] = a5;
      sQPp[wave][lane][6] = a6; sQPp[wave][lane][7] = a7;
    }
  }
  __syncthreads();   // sync#5

  // ====== QP tail: full wave 0 (64 lanes = 64 elems), Schur ADMM ======
  if (tid >= 64) return;
  const int p = tid >> 4, mm = tid & 15;
  const int e = blockIdx.x * 64 + tid;
  float gh0 = sQPp[2 * p][mm][0] + sQPp[2 * p + 1][mm][0];
  float gh1 = sQPp[2 * p][mm][1] + sQPp[2 * p + 1][mm][1];
  float gv0 = sQPp[2 * p][mm][2] + sQPp[2 * p + 1][mm][2];
  float gv1 = sQPp[2 * p][mm][3] + sQPp[2 * p + 1][mm][3];
  float ghx = sQPp[2 * p][mm][4] + sQPp[2 * p + 1][mm][4];
  float gvx = sQPp[2 * p][mm][5] + sQPp[2 * p + 1][mm][5];
  float V   = 0.5f * (sQPp[2 * p][mm][6] + sQPp[2 * p + 1][mm][6]);
  float H   = sQPp[2 * p][mm][7] + sQPp[2 * p + 1][mm][7] + sC[C_HB4];
  float un0 = sQPp[2 * p][mm][8], un1 = sQPp[2 * p][mm][9];
  out[98304 + e]  = V;
  out[163840 + e] = H;

  const float im = 1.0f / 1.2f;
  const float sg = 1e-6f;

  float lo0 = ghx - H;
  float hi1 = gvx - V;
  float lo2 = ghx * im - H;
  float hi3 = gvx * im - V;
  float qv0 = -2.f * un0, qv1 = -2.f * un1;

  const float d  = 2.f + sg;
  const float rd = 1.f / d;
  const float al = 1.f + im * im;
  const float be = al * (1.f - rd);
  float S00 = be * (gh0 * gh0 + gv0 * gv0) + d;
  float S11 = be * (gh1 * gh1 + gv1 * gv1) + d;
  float S01 = be * (gh0 * gh1 + gv0 * gv1);
  float idet = 1.f / (S00 * S11 - S01 * S01);
  float i00 = S11 * idet, i11 = S00 * idet, i01 = -S01 * idet;

  float X0 = 0.f, X1 = 0.f, X2 = 0.f, X3 = 0.f, X4 = 0.f, X5 = 0.f;
  float Z[8] = {0.f, 0.f, 0.f, 0.f, 0.f, 0.f, 0.f, 0.f};
  float Y[8] = {0.f, 0.f, 0.f, 0.f, 0.f, 0.f, 0.f, 0.f};

#pragma unroll 1
  for (int it = 0; it < 80; ++it) {
    float t0 = Z[0] - Y[0], t1 = Z[1] - Y[1], t2 = Z[2] - Y[2], t3 = Z[3] - Y[3];
    float t4 = Z[4] - Y[4], t5 = Z[5] - Y[5], t6 = Z[6] - Y[6], t7 = Z[7] - Y[7];
    float tauh = t0 + im * t2, tauv = t1 + im * t3;
    float b0 = sg * X0 - qv0 + gh0 * tauh + gv0 * tauv;
    float b1 = sg * X1 - qv1 + gh1 * tauh + gv1 * tauv;
    float b2 = sg * X2 - 100.f - t1 + t4;
    float b3 = sg * X3 - 100.f - t3 + t5;
    float b4 = sg * X4 - 50.f + t0 + t6;
    float b5 = sg * X5 - 50.f + t2 + t7;
    float pp = b2 + im * b3;
    float s2 = b4 + im * b5;
    float cb0 = gh0 * s2 - gv0 * pp;
    float cb1 = gh1 * s2 - gv1 * pp;
    float u0b = b0 - cb0 * rd;
    float u1b = b1 - cb1 * rd;
    X0 = i00 * u0b + i01 * u1b;
    X1 = i01 * u0b + i11 * u1b;
    float gdH = gh0 * X0 + gh1 * X1;
    float gdV = gv0 * X0 + gv1 * X1;
    X2 = (b2 + gdV) * rd;
    X3 = (b3 + im * gdV) * rd;
    X4 = (b4 - gdH) * rd;
    X5 = (b5 - im * gdH) * rd;
    float zt0 = gdH + X4;
    float zt1 = gdV - X2;
    float zt2 = gdH * im + X5;
    float zt3 = gdV * im - X3;

    float v, zn;
    v = zt0 + Y[0]; zn = fmaxf(v, lo0); Y[0] += zt0 - zn; Z[0] = zn;
    v = zt1 + Y[1]; zn = fminf(v, hi1); Y[1] += zt1 - zn; Z[1] = zn;
    v = zt2 + Y[2]; zn = fmaxf(v, lo2); Y[2] += zt2 - zn; Z[2] = zn;
    v = zt3 + Y[3]; zn = fminf(v, hi3); Y[3] += zt3 - zn; Z[3] = zn;
    v = X2 + Y[4];  zn = fmaxf(v, 0.f); Y[4] += X2 - zn;  Z[4] = zn;
    v = X3 + Y[5];  zn = fmaxf(v, 0.f); Y[5] += X3 - zn;  Z[5] = zn;
    v = X4 + Y[6];  zn = fmaxf(v, 0.f); Y[6] += X4 - zn;  Z[6] = zn;
    v = X5 + Y[7];  zn = fmaxf(v, 0.f); Y[7] += X5 - zn;  Z[7] = zn;
  }

  float relax = 0.5f * (X2 + X3);
  const float cc = 0.5f * (1.f + im);
  float Vdot = cc * (gv0 * X0 + gv1 * X1 - gvx);
  float Hdot = cc * (gh0 * X0 + gh1 * X1 - ghx);

  out[2 * e]      = X0;
  out[2 * e + 1]  = X1;
  out[65536 + e]  = relax;
  out[131072 + e] = Vdot;
  out[196608 + e] = Hdot;
}

extern "C" void kernel_launch(void* const* d_in, const int* in_sizes, int n_in,
                              void* d_out, int out_size, void* d_ws, size_t ws_size,
                              hipStream_t stream) {
  float* out = (float*)d_out;
  _Float16* wsp = (_Float16*)d_ws;
  prep_kernel<<<16, 256, 0, stream>>>(
      d_in[0], d_in[1], d_in[3], d_in[5], d_in[7], d_in[9],
      d_in[2], d_in[4], d_in[6], d_in[8], d_in[10], d_in[11], d_in[12],
      d_in[13], d_in[14], wsp);
  main_kernel<<<512, 512, 0, stream>>>(d_in[0], wsp, out);
}